// Round 6
// baseline (442.313 us; speedup 1.0000x reference)
//
#include <hip/hip_runtime.h>
#include <hip/hip_bf16.h>
#include <stdint.h>

#define LL 1024
#define BB 256
#define CC 96
#define HH 768
#define NW 9216   // CC*CC
#define NTOT 9408 // NW + 2*CC
#define SEGS 8
#define SEGLEN 128
#define CHPB 15   // chain slots per batch: 8 fw + 7 bw

typedef __attribute__((ext_vector_type(4))) float floatx4;
typedef __attribute__((ext_vector_type(2))) float floatx2;
typedef __attribute__((ext_vector_type(8))) short short8;

#define KAPPA 0x1p-16f
#define NEG_LOG_KAPPA 11.090354888959125f  // 16*ln2

__device__ __forceinline__ unsigned short f2bf(float f) {
  uint32_t u = __float_as_uint(f);
  return (unsigned short)((u + 0x7FFFu + ((u >> 16) & 1u)) >> 16);
}

// ---------------- fused bf16 MFMA GEMM: out = hidden @ [Wt;Ws;We]^T + bias ---
#define GA_LD 40

__global__ __launch_bounds__(256) void gemm_mfma(
    const float* __restrict__ hidden, const float* __restrict__ Wt,
    const float* __restrict__ Ws, const float* __restrict__ We,
    const float* __restrict__ bt, const float* __restrict__ bs,
    const float* __restrict__ be, float* __restrict__ trans,
    float* __restrict__ tstart, float* __restrict__ tend) {
  __shared__ __align__(16) unsigned short As[128 * GA_LD];
  __shared__ __align__(16) unsigned short Bs[128 * GA_LD];
  const int t = threadIdx.x;
  const int lane = t & 63, wid = t >> 6;
  const int wm = wid >> 1, wn = wid & 1;
  const int l15 = lane & 15, qd = lane >> 4;
  const int m0 = blockIdx.y * 128, n0 = blockIdx.x * 128;
  const int srow = t >> 1, shalf = t & 1;

  floatx4 acc[4][4];
#pragma unroll
  for (int i = 0; i < 4; ++i)
#pragma unroll
    for (int j = 0; j < 4; ++j) acc[i][j] = (floatx4){0.f, 0.f, 0.f, 0.f};

  const int r = n0 + srow;
  const float* bsrc = (r < NW)        ? Wt + (size_t)r * HH
                      : (r < NW + CC) ? Ws + (size_t)(r - NW) * HH
                      : (r < NTOT)    ? We + (size_t)(r - NW - CC) * HH
                                      : nullptr;
  const float* asrc = hidden + (size_t)(m0 + srow) * HH;
  const int sidx = srow * GA_LD + shalf * 16;

  for (int k0 = 0; k0 < HH; k0 += 32) {
    __syncthreads();
    {
      const float4* s4 = (const float4*)(asrc + k0 + shalf * 16);
      uint32_t w[8];
#pragma unroll
      for (int u = 0; u < 4; ++u) {
        float4 v = s4[u];
        w[2 * u] = (uint32_t)f2bf(v.x) | ((uint32_t)f2bf(v.y) << 16);
        w[2 * u + 1] = (uint32_t)f2bf(v.z) | ((uint32_t)f2bf(v.w) << 16);
      }
      *(uint4*)&As[sidx] = make_uint4(w[0], w[1], w[2], w[3]);
      *(uint4*)&As[sidx + 8] = make_uint4(w[4], w[5], w[6], w[7]);
    }
    {
      uint32_t w[8];
      if (bsrc) {
        const float4* s4 = (const float4*)(bsrc + k0 + shalf * 16);
#pragma unroll
        for (int u = 0; u < 4; ++u) {
          float4 v = s4[u];
          w[2 * u] = (uint32_t)f2bf(v.x) | ((uint32_t)f2bf(v.y) << 16);
          w[2 * u + 1] = (uint32_t)f2bf(v.z) | ((uint32_t)f2bf(v.w) << 16);
        }
      } else {
#pragma unroll
        for (int u = 0; u < 8; ++u) w[u] = 0u;
      }
      *(uint4*)&Bs[sidx] = make_uint4(w[0], w[1], w[2], w[3]);
      *(uint4*)&Bs[sidx + 8] = make_uint4(w[4], w[5], w[6], w[7]);
    }
    __syncthreads();
    short8 af[4], bf[4];
#pragma unroll
    for (int i = 0; i < 4; ++i)
      af[i] = *(const short8*)&As[(64 * wm + 16 * i + l15) * GA_LD + qd * 8];
#pragma unroll
    for (int j = 0; j < 4; ++j)
      bf[j] = *(const short8*)&Bs[(64 * wn + 16 * j + l15) * GA_LD + qd * 8];
#pragma unroll
    for (int i = 0; i < 4; ++i)
#pragma unroll
      for (int j = 0; j < 4; ++j)
        acc[i][j] = __builtin_amdgcn_mfma_f32_16x16x32_bf16(af[i], bf[j],
                                                            acc[i][j], 0, 0, 0);
  }

#pragma unroll
  for (int j = 0; j < 4; ++j) {
    int n = n0 + 64 * wn + 16 * j + l15;
    if (n >= NTOT) continue;
    float bv;
    float* dst;
    int ldo;
    if (n < NW) {
      bv = bt[n]; dst = trans + n; ldo = NW;
    } else if (n < NW + CC) {
      bv = bs[n - NW]; dst = tstart + (n - NW); ldo = CC;
    } else {
      bv = be[n - NW - CC]; dst = tend + (n - NW - CC); ldo = CC;
    }
#pragma unroll
    for (int i = 0; i < 4; ++i)
#pragma unroll
      for (int rr = 0; rr < 4; ++rr) {
        int m = m0 + 64 * wm + 16 * i + 4 * qd + rr;
        dst[(size_t)m * ldo] = acc[i][j][rr] + bv;
      }
  }
}

// ---------------- helpers --------------------------------------------------
__device__ __forceinline__ float wredf(float v) {
#pragma unroll
  for (int m = 32; m >= 1; m >>= 1) v += __shfl_xor(v, m);
  return v;
}
__device__ __forceinline__ int wredi(int v) {
#pragma unroll
  for (int m = 32; m >= 1; m >>= 1) v += __shfl_xor(v, m);
  return v;
}
__device__ __forceinline__ float bcast0(float x) {
  return __uint_as_float(__builtin_amdgcn_readfirstlane(__float_as_uint(x)));
}
__device__ __forceinline__ int get_len(const void* mask, int b, int l) {
  int cnt = 0;
  unsigned w0 = *(const unsigned*)mask;
  if (w0 == 1u) {
    const int* m32 = (const int*)mask;
    for (int i = l; i < LL; i += 64) cnt += (m32[i * BB + b] != 0);
  } else if (w0 == 0x01010101u) {
    const unsigned char* m8 = (const unsigned char*)mask;
    for (int i = l; i < LL; i += 64) cnt += (m8[i * BB + b] != 0);
  } else {
    const float* mf = (const float*)mask;
    for (int i = l; i < LL; i += 64) cnt += (mf[i * BB + b] != 0.f);
  }
  return wredi(cnt);
}

// ---------------- segment chain kernel: 2048 blocks x 1 wave ----------------
// DUAL-CHAIN waves: each wave advances TWO same-direction segments of the
// same batch (they share the identical T2 register slice), interleaved
// step-by-step so one chain's LDS write->read turnaround hides under the
// other's reads/FMAs. Residency is pinned at ~1 wave/SIMD by the 144-reg
// T2 floor (R0-R5 data), so extra ILP must come from inside the wave.
// blk = b*8 + k. k<4: fw pair (segs k, k+4). k=4..6: bw pair (k-3, k+1).
// k=7: bw solo seg 4. Slots: fw seg s -> s, bw seg s -> 7+s (compose
// kernel unchanged). Per-chain math is bit-identical to the single-chain
// version.
__global__ __launch_bounds__(64, 1) void crf_chain(
    const float* __restrict__ emit, const void* __restrict__ mask,
    const float* __restrict__ trans, const float* __restrict__ tstart,
    float* __restrict__ xvec, float* __restrict__ lsc) {
  const int blk = blockIdx.x;
  const int b = blk >> 3;
  const int k = blk & 7;
  const bool isfw = (k < 4);
  int segA, segB;
  bool hasB;
  if (isfw) {
    segA = k; segB = k + 4; hasB = true;
  } else if (k < 7) {
    segA = k - 3; segB = k + 1; hasB = true;
  } else {
    segA = 4; segB = 0; hasB = false;
  }
  const int l = threadIdx.x;
  const int pr = l >> 1, s = l & 1;

  __shared__ __align__(16) float ebA[2][8][CC];
  __shared__ __align__(16) float uAv[CC];  // after ebA: E overread lands here
  __shared__ __align__(16) float ebB[2][8][CC];
  __shared__ __align__(16) float uBv[CC];

  const int len = get_len(mask, b, l);
  const int loA = segA * SEGLEN + 1;
  const int hiA = min((segA + 1) * SEGLEN, len - 1);
  const int loB = segB * SEGLEN + 1;
  const int hiB = hasB ? min((segB + 1) * SEGLEN, len - 1) : -1;
  const int cidA = b * CHPB + (isfw ? segA : 7 + segA);
  const int cidB = b * CHPB + (isfw ? segB : 7 + segB);
  const bool actB = hasB && (hiB >= loB);
  const int nA = hiA - loA + 1;
  const int nB = actB ? (hiB - loB + 1) : 0;

  if (hasB && !actB) {  // empty B -> identity; composition skips it
    float* xo = xvec + (size_t)cidB * CC;
    xo[l] = 1.f;
    if (l < 32) xo[l + 64] = 1.f;
    if (l == 0) lsc[cidB] = 0.f;
  }
  if (hiA < loA) {  // defensive (A segments are always active for len>=512)
    float* xo = xvec + (size_t)cidA * CC;
    xo[l] = 1.f;
    if (l < 32) xo[l + 64] = 1.f;
    if (l == 0) lsc[cidA] = 0.f;
    return;
  }

  // ---- T registers (shared by both chains; direction-dependent slice) ----
  const float* tb = trans + (size_t)b * (CC * CC);
  floatx2 T2[3][24];
  if (isfw) {
#pragma unroll
    for (int j = 0; j < 24; ++j) {
      const float* r0 = tb + (48 * s + 2 * j) * CC + 3 * pr;
      const float* r1 = r0 + CC;
#pragma unroll
      for (int o = 0; o < 3; ++o)
        T2[o][j] = (floatx2){__expf(r0[o]), __expf(r1[o])};
    }
  } else {
#pragma unroll
    for (int o = 0; o < 3; ++o) {
      const float* row = tb + (3 * pr + o) * CC + 48 * s;
#pragma unroll
      for (int j = 0; j < 24; ++j)
        T2[o][j] = (floatx2){__expf(row[2 * j]), __expf(row[2 * j + 1])};
    }
  }

  const float4* e4 = (const float4*)emit;
  const int eoff = 3 * pr + 2 * s;
  float LA = 0.f, pvA = 1.f, LB = 0.f, pvB = 1.f;

#define CLOB asm volatile("" ::: "memory")

  auto STAGE = [&](float (*eb)[8][CC], int baserow, int slot) {
#pragma unroll
    for (int uu = 0; uu < 3; ++uu) {
      int v = l + 64 * uu;
      int rw = v / 24, c4 = v - 24 * rw;
      float4 vv = e4[((baserow + rw) * BB + b) * 24 + c4];
      floatx4 o = {__expf(vv.x) * KAPPA, __expf(vv.y) * KAPPA,
                   __expf(vv.z) * KAPPA, __expf(vv.w) * KAPPA};
      *(floatx4*)&eb[slot][rw][c4 * 4] = o;
    }
  };

  auto DOT = [&](const float* ub, float& a0, float& a1, float& a2) {
    const floatx4* up = (const floatx4*)&ub[48 * s];
    floatx2 A0 = {0.f, 0.f}, B0 = {0.f, 0.f};
    floatx2 A1 = {0.f, 0.f}, B1 = {0.f, 0.f};
    floatx2 A2 = {0.f, 0.f}, B2 = {0.f, 0.f};
#pragma unroll
    for (int j4 = 0; j4 < 12; ++j4) {
      floatx4 U = up[j4];
      floatx2 lo2 = {U.x, U.y}, hi2 = {U.z, U.w};
      A0 += lo2 * T2[0][2 * j4]; B0 += hi2 * T2[0][2 * j4 + 1];
      A1 += lo2 * T2[1][2 * j4]; B1 += hi2 * T2[1][2 * j4 + 1];
      A2 += lo2 * T2[2][2 * j4]; B2 += hi2 * T2[2][2 * j4 + 1];
    }
    floatx2 S0 = A0 + B0, S1 = A1 + B1, S2 = A2 + B2;
    a0 = S0.x + S0.y; a1 = S1.x + S1.y; a2 = S2.x + S2.y;
    a0 += __shfl_xor(a0, 1);
    a1 += __shfl_xor(a1, 1);
    a2 += __shfl_xor(a2, 1);
  };

  auto STEPF = [&](int i, int jjv, float& pvv, float& Lv,
                   float (*eb)[8][CC], float* ub) {
    float invP = 1.f;
    if ((jjv & 3) == 0) { invP = 1.0f / pvv; Lv += __logf(pvv); }
    float a0, a1, a2;
    DOT(ub, a0, a1, a2);
    floatx2 E = *(const floatx2*)&eb[(i >> 3) & 1][i & 7][eoff];
    float o0 = a0 * E.x * invP;
    if (((jjv + 1) & 3) == 0) pvv = bcast0(o0);
    if (s == 0) {
      floatx2 wv = {o0, a1 * E.y * invP};
      *(floatx2*)&ub[3 * pr] = wv;
    } else {
      ub[3 * pr + 2] = a2 * E.x * invP;
    }
  };

  auto STEPB = [&](int i, int lo, int jjv, float& pvv, float& Lv,
                   float (*eb)[8][CC], float* ub) {
    float invP = 1.f;
    if ((jjv & 3) == 0) { invP = 1.0f / pvv; Lv += __logf(pvv); }
    float a0, a1, a2;
    DOT(ub, a0, a1, a2);
    floatx2 E = (i > lo)
        ? *(const floatx2*)&eb[((i - 1) >> 3) & 1][(i - 1) & 7][eoff]
        : (floatx2){1.f, 1.f};
    float o0 = a0 * E.x * invP;
    if (((jjv + 1) & 3) == 0) pvv = bcast0(o0);
    if (s == 0) {
      floatx2 wv = {o0, a1 * E.y * invP};
      *(floatx2*)&ub[3 * pr] = wv;
    } else {
      ub[3 * pr + 2] = a2 * E.x * invP;
    }
  };

  if (isfw) {
    const int bA0 = loA & ~7;
    STAGE(ebA, bA0, (bA0 >> 3) & 1);
    if (actB) {
      const int bB0 = loB & ~7;
      STAGE(ebB, bB0, (bB0 >> 3) & 1);
    }
    if (segA == 0) {
      float a00 = emit[(size_t)b * CC] + tstart[b * CC];
      LA = a00;
      float v = emit[(size_t)b * CC + l] + tstart[b * CC + l];
      uAv[l] = __expf(v - a00);
      if (l < 32) {
        int c2 = l + 64;
        float v2 = emit[(size_t)b * CC + c2] + tstart[b * CC + c2];
        uAv[c2] = __expf(v2 - a00);
      }
    } else {
      uAv[l] = 1.f;
      if (l < 32) uAv[l + 64] = 1.f;
    }
    if (actB) {
      uBv[l] = 1.f;
      if (l < 32) uBv[l + 64] = 1.f;
    }
    CLOB;
    int jj = 1;
    int iA = loA, iB = loB;
    const int nmin = actB ? min(nA, nB) : 0;
    for (; jj <= nmin; ++jj, ++iA, ++iB) {
      bool st = false;
      if ((iA & 7) == 0) { STAGE(ebA, iA, (iA >> 3) & 1); st = true; }
      if ((iB & 7) == 0) { STAGE(ebB, iB, (iB >> 3) & 1); st = true; }
      if (st) CLOB;
      STEPF(iA, jj, pvA, LA, ebA, uAv);
      STEPF(iB, jj, pvB, LB, ebB, uBv);
      CLOB;
    }
    int jjA = jj;
    for (; iA <= hiA; ++iA, ++jjA) {
      if ((iA & 7) == 0) { STAGE(ebA, iA, (iA >> 3) & 1); CLOB; }
      STEPF(iA, jjA, pvA, LA, ebA, uAv);
      CLOB;
    }
    int jjB = jj;
    for (; actB && iB <= hiB; ++iB, ++jjB) {
      if ((iB & 7) == 0) { STAGE(ebB, iB, (iB >> 3) & 1); CLOB; }
      STEPF(iB, jjB, pvB, LB, ebB, uBv);
      CLOB;
    }
  } else {
    const int cA0 = hiA & ~7;
    STAGE(ebA, cA0, (cA0 >> 3) & 1);
    if (actB) {
      const int cB0 = hiB & ~7;
      STAGE(ebB, cB0, (cB0 >> 3) & 1);
    }
    CLOB;
    uAv[l] = ebA[(hiA >> 3) & 1][hiA & 7][l];
    if (l < 32) uAv[l + 64] = ebA[(hiA >> 3) & 1][hiA & 7][l + 64];
    if (actB) {
      uBv[l] = ebB[(hiB >> 3) & 1][hiB & 7][l];
      if (l < 32) uBv[l + 64] = ebB[(hiB >> 3) & 1][hiB & 7][l + 64];
    }
    CLOB;
    int jj = 1;
    int iA = hiA, iB = hiB;
    const int nmin = actB ? min(nA, nB) : 0;
    for (; jj <= nmin; ++jj, --iA, --iB) {
      bool st = false;
      if ((iA & 7) == 0 && iA > loA) {
        STAGE(ebA, iA - 8, ((iA >> 3) & 1) ^ 1); st = true;
      }
      if ((iB & 7) == 0 && iB > loB) {
        STAGE(ebB, iB - 8, ((iB >> 3) & 1) ^ 1); st = true;
      }
      if (st) CLOB;
      STEPB(iA, loA, jj, pvA, LA, ebA, uAv);
      STEPB(iB, loB, jj, pvB, LB, ebB, uBv);
      CLOB;
    }
    int jjA = jj;
    for (; iA >= loA; --iA, ++jjA) {
      if ((iA & 7) == 0 && iA > loA) {
        STAGE(ebA, iA - 8, ((iA >> 3) & 1) ^ 1); CLOB;
      }
      STEPB(iA, loA, jjA, pvA, LA, ebA, uAv);
      CLOB;
    }
    int jjB = jj;
    for (; actB && iB >= loB; --iB, ++jjB) {
      if ((iB & 7) == 0 && iB > loB) {
        STAGE(ebB, iB - 8, ((iB >> 3) & 1) ^ 1); CLOB;
      }
      STEPB(iB, loB, jjB, pvB, LB, ebB, uBv);
      CLOB;
    }
  }

  CLOB;
  {
    float* xo = xvec + (size_t)cidA * CC;
    xo[l] = uAv[l];
    if (l < 32) xo[l + 64] = uAv[l + 64];
    if (l == 0) lsc[cidA] = LA + (float)nA * NEG_LOG_KAPPA;
  }
  if (actB) {
    float* xo = xvec + (size_t)cidB * CC;
    xo[l] = uBv[l];
    if (l < 32) xo[l + 64] = uBv[l + 64];
    if (l == 0) lsc[cidB] = LB + (float)nB * NEG_LOG_KAPPA;
  }
}

// ---------------- composition + score: 256 blocks x 1 wave ------------------
__global__ __launch_bounds__(64) void crf_compose(
    const float* __restrict__ emit, const int* __restrict__ target,
    const void* __restrict__ mask, const float* __restrict__ trans,
    const float* __restrict__ tstart, const float* __restrict__ tend,
    const float* __restrict__ xvec, const float* __restrict__ lsc,
    float* __restrict__ out) {
  const int b = blockIdx.x;
  const int l = threadIdx.x;
  const int len = get_len(mask, b, l);

  // telescope: x_s = a_s * e^{g_s} * (b_s . x_{s-1})/(b_s . 1)
  float Lam = lsc[b * CHPB + 0];
  const float* xcur = xvec + (size_t)(b * CHPB + 0) * CC;
  for (int s2 = 1; s2 < SEGS; ++s2) {
    if (s2 * SEGLEN + 1 > len - 1) break;  // empty segment = identity
    const float* bh = xvec + (size_t)(b * CHPB + (SEGS - 1) + s2) * CC;
    const float* ah = xvec + (size_t)(b * CHPB + s2) * CC;
    float pn = bh[l] * xcur[l];
    float pd = bh[l];
    if (l < 32) {
      pn += bh[l + 64] * xcur[l + 64];
      pd += bh[l + 64];
    }
    float num = wredf(pn), den = wredf(pd);
    Lam += __logf(num / den) + lsc[b * CHPB + s2];
    xcur = ah;
  }
  float zp = xcur[l] * __expf(tend[b * CC + l]);
  if (l < 32) zp += xcur[l + 64] * __expf(tend[b * CC + l + 64]);
  float logz = Lam + __logf(wredf(zp));

  // gold-path score
  const float* tb = trans + (size_t)b * (CC * CC);
  float sc = 0.f;
  for (int i = l; i < len; i += 64) {
    int tg = target[i * BB + b];
    sc += emit[((size_t)i * BB + b) * CC + tg];
    if (i >= 1) sc += tb[target[(i - 1) * BB + b] * CC + tg];
  }
  float score = wredf(sc);
  if (l == 0) {
    score += tstart[b * CC + target[b]] +
             tend[b * CC + target[(len - 1) * BB + b]];
    atomicAdd(out, (logz - score) * (1.0f / 256.0f));
  }
}

extern "C" void kernel_launch(void* const* d_in, const int* in_sizes, int n_in,
                              void* d_out, int out_size, void* d_ws, size_t ws_size,
                              hipStream_t stream) {
  const float* emit = (const float*)d_in[0];
  const float* hidden = (const float*)d_in[1];
  const int* target = (const int*)d_in[2];
  const void* mask = d_in[3];
  const float* Wt = (const float*)d_in[4];
  const float* bt = (const float*)d_in[5];
  const float* Ws = (const float*)d_in[6];
  const float* bs = (const float*)d_in[7];
  const float* We = (const float*)d_in[8];
  const float* be = (const float*)d_in[9];

  float* trans_ws = (float*)d_ws;                  // 256*9216
  float* ts_ws = trans_ws + (size_t)BB * CC * CC;  // 256*96
  float* te_ws = ts_ws + (size_t)BB * CC;          // 256*96
  float* xvec = te_ws + (size_t)BB * CC;           // 3840*96
  float* lsc = xvec + (size_t)BB * CHPB * CC;      // 3840

  hipMemsetAsync(d_out, 0, sizeof(float), stream);

  gemm_mfma<<<dim3((NTOT + 127) / 128, 2), 256, 0, stream>>>(
      hidden, Wt, Ws, We, bt, bs, be, trans_ws, ts_ws, te_ws);

  crf_chain<<<BB * 8, 64, 0, stream>>>(emit, mask, trans_ws, ts_ws, xvec, lsc);

  crf_compose<<<BB, 64, 0, stream>>>(emit, target, mask, trans_ws, ts_ws, te_ws,
                                     xvec, lsc, (float*)d_out);
}

// Round 7
// 393.828 us; speedup vs baseline: 1.1231x; 1.1231x over previous
//
#include <hip/hip_runtime.h>
#include <hip/hip_bf16.h>
#include <stdint.h>

#define LL 1024
#define BB 256
#define CC 96
#define HH 768
#define NW 9216   // CC*CC
#define NTOT 9408 // NW + 2*CC
#define SEGS 8
#define SEGLEN 128
#define CHPB 15   // chain slots per batch: 8 fw + 7 bw

typedef __attribute__((ext_vector_type(4))) float floatx4;
typedef __attribute__((ext_vector_type(2))) float floatx2;
typedef __attribute__((ext_vector_type(8))) short short8;

#define KAPPA 0x1p-16f
#define NEG_LOG_KAPPA 11.090354888959125f  // 16*ln2

__device__ __forceinline__ unsigned short f2bf(float f) {
  uint32_t u = __float_as_uint(f);
  return (unsigned short)((u + 0x7FFFu + ((u >> 16) & 1u)) >> 16);
}

// ---------------- fused bf16 MFMA GEMM: out = hidden @ [Wt;Ws;We]^T + bias ---
#define GA_LD 40

__global__ __launch_bounds__(256) void gemm_mfma(
    const float* __restrict__ hidden, const float* __restrict__ Wt,
    const float* __restrict__ Ws, const float* __restrict__ We,
    const float* __restrict__ bt, const float* __restrict__ bs,
    const float* __restrict__ be, float* __restrict__ trans,
    float* __restrict__ tstart, float* __restrict__ tend) {
  __shared__ __align__(16) unsigned short As[128 * GA_LD];
  __shared__ __align__(16) unsigned short Bs[128 * GA_LD];
  const int t = threadIdx.x;
  const int lane = t & 63, wid = t >> 6;
  const int wm = wid >> 1, wn = wid & 1;
  const int l15 = lane & 15, qd = lane >> 4;
  const int m0 = blockIdx.y * 128, n0 = blockIdx.x * 128;
  const int srow = t >> 1, shalf = t & 1;

  floatx4 acc[4][4];
#pragma unroll
  for (int i = 0; i < 4; ++i)
#pragma unroll
    for (int j = 0; j < 4; ++j) acc[i][j] = (floatx4){0.f, 0.f, 0.f, 0.f};

  const int r = n0 + srow;
  const float* bsrc = (r < NW)        ? Wt + (size_t)r * HH
                      : (r < NW + CC) ? Ws + (size_t)(r - NW) * HH
                      : (r < NTOT)    ? We + (size_t)(r - NW - CC) * HH
                                      : nullptr;
  const float* asrc = hidden + (size_t)(m0 + srow) * HH;
  const int sidx = srow * GA_LD + shalf * 16;

  for (int k0 = 0; k0 < HH; k0 += 32) {
    __syncthreads();
    {
      const float4* s4 = (const float4*)(asrc + k0 + shalf * 16);
      uint32_t w[8];
#pragma unroll
      for (int u = 0; u < 4; ++u) {
        float4 v = s4[u];
        w[2 * u] = (uint32_t)f2bf(v.x) | ((uint32_t)f2bf(v.y) << 16);
        w[2 * u + 1] = (uint32_t)f2bf(v.z) | ((uint32_t)f2bf(v.w) << 16);
      }
      *(uint4*)&As[sidx] = make_uint4(w[0], w[1], w[2], w[3]);
      *(uint4*)&As[sidx + 8] = make_uint4(w[4], w[5], w[6], w[7]);
    }
    {
      uint32_t w[8];
      if (bsrc) {
        const float4* s4 = (const float4*)(bsrc + k0 + shalf * 16);
#pragma unroll
        for (int u = 0; u < 4; ++u) {
          float4 v = s4[u];
          w[2 * u] = (uint32_t)f2bf(v.x) | ((uint32_t)f2bf(v.y) << 16);
          w[2 * u + 1] = (uint32_t)f2bf(v.z) | ((uint32_t)f2bf(v.w) << 16);
        }
      } else {
#pragma unroll
        for (int u = 0; u < 8; ++u) w[u] = 0u;
      }
      *(uint4*)&Bs[sidx] = make_uint4(w[0], w[1], w[2], w[3]);
      *(uint4*)&Bs[sidx + 8] = make_uint4(w[4], w[5], w[6], w[7]);
    }
    __syncthreads();
    short8 af[4], bf[4];
#pragma unroll
    for (int i = 0; i < 4; ++i)
      af[i] = *(const short8*)&As[(64 * wm + 16 * i + l15) * GA_LD + qd * 8];
#pragma unroll
    for (int j = 0; j < 4; ++j)
      bf[j] = *(const short8*)&Bs[(64 * wn + 16 * j + l15) * GA_LD + qd * 8];
#pragma unroll
    for (int i = 0; i < 4; ++i)
#pragma unroll
      for (int j = 0; j < 4; ++j)
        acc[i][j] = __builtin_amdgcn_mfma_f32_16x16x32_bf16(af[i], bf[j],
                                                            acc[i][j], 0, 0, 0);
  }

#pragma unroll
  for (int j = 0; j < 4; ++j) {
    int n = n0 + 64 * wn + 16 * j + l15;
    if (n >= NTOT) continue;
    float bv;
    float* dst;
    int ldo;
    if (n < NW) {
      bv = bt[n]; dst = trans + n; ldo = NW;
    } else if (n < NW + CC) {
      bv = bs[n - NW]; dst = tstart + (n - NW); ldo = CC;
    } else {
      bv = be[n - NW - CC]; dst = tend + (n - NW - CC); ldo = CC;
    }
#pragma unroll
    for (int i = 0; i < 4; ++i)
#pragma unroll
      for (int rr = 0; rr < 4; ++rr) {
        int m = m0 + 64 * wm + 16 * i + 4 * qd + rr;
        dst[(size_t)m * ldo] = acc[i][j][rr] + bv;
      }
  }
}

// ---------------- helpers --------------------------------------------------
__device__ __forceinline__ float wredf(float v) {
#pragma unroll
  for (int m = 32; m >= 1; m >>= 1) v += __shfl_xor(v, m);
  return v;
}
__device__ __forceinline__ int wredi(int v) {
#pragma unroll
  for (int m = 32; m >= 1; m >>= 1) v += __shfl_xor(v, m);
  return v;
}
__device__ __forceinline__ float bcast0(float x) {
  return __uint_as_float(__builtin_amdgcn_readfirstlane(__float_as_uint(x)));
}
// quad sum via DPP (pure VALU: keeps the DS pipe clear). All 4 lanes of a
// quad end with the same value (FP add is commutative bitwise).
__device__ __forceinline__ float qsum4(float x) {
  x += __int_as_float(__builtin_amdgcn_mov_dpp(__float_as_int(x), 0xB1, 0xF, 0xF, false));
  x += __int_as_float(__builtin_amdgcn_mov_dpp(__float_as_int(x), 0x4E, 0xF, 0xF, false));
  return x;
}
__device__ __forceinline__ int get_len(const void* mask, int b, int l) {
  int cnt = 0;
  unsigned w0 = *(const unsigned*)mask;
  if (w0 == 1u) {
    const int* m32 = (const int*)mask;
    for (int i = l; i < LL; i += 64) cnt += (m32[i * BB + b] != 0);
  } else if (w0 == 0x01010101u) {
    const unsigned char* m8 = (const unsigned char*)mask;
    for (int i = l; i < LL; i += 64) cnt += (m8[i * BB + b] != 0);
  } else {
    const float* mf = (const float*)mask;
    for (int i = l; i < LL; i += 64) cnt += (mf[i * BB + b] != 0.f);
  }
  return wredi(cnt);
}

// ---------------- segment chain kernel: 3840 blocks x 1 wave ----------------
// cid = b*15 + k. k<8: forward segment k; k>=8: backward segment k-7.
// SPLIT=4 quad decomposition: quad g (=l>>2) owns 6 output tags 6g..6g+5;
// lane q (=l&3) reads only u[24q..24q+23] (6 ds_read_b128 vs 12) and keeps
// T[i][j] for its 24 i x 6 j = 144 regs (invariant). Quad-reduce is DPP
// (VALU), removing shfl from the in-order DS queue. Rationale: R0/R1/R6
// counters show a per-CU DS-throughput bottleneck (total VALU-busy-time
// conserved across wave-count changes); this halves DS cycles per step.
__global__ __launch_bounds__(64, 2) void crf_chain(
    const float* __restrict__ emit, const void* __restrict__ mask,
    const float* __restrict__ trans, const float* __restrict__ tstart,
    float* __restrict__ xvec, float* __restrict__ lsc) {
  const int cid = blockIdx.x;
  const int b = cid / CHPB;
  const int k = cid - CHPB * b;
  const bool isfw = (k < SEGS);
  const int seg = isfw ? k : (k - (SEGS - 1));
  const int l = threadIdx.x;
  const int g = l >> 2, q = l & 3;

  __shared__ __align__(16) float ebuf[2][8][CC];  // exp(emit)*kappa ring
  __shared__ __align__(16) float u_lds[CC];       // (placed after ebuf: E overread lands here)

  const int len = get_len(mask, b, l);
  const int lo = seg * SEGLEN + 1;
  const int hi = min((seg + 1) * SEGLEN, len - 1);
  float* xout = xvec + (size_t)cid * CC;
  if (hi < lo) {  // empty segment -> identity; composition skips it
    xout[l] = 1.f;
    if (l < 32) xout[l + 64] = 1.f;
    if (l == 0) lsc[cid] = 0.f;
    return;
  }
  const int n = hi - lo + 1;

  // ---- T registers: fw: T2[t][m] = {expT[24q+2m][6g+t], expT[24q+2m+1][6g+t]}
  //                   bw: T2[t][m] = {expT[6g+t][24q+2m], expT[6g+t][24q+2m+1]}
  const float* tb = trans + (size_t)b * (CC * CC);
  floatx2 T2[6][12];
  if (isfw) {
#pragma unroll
    for (int t = 0; t < 6; ++t)
#pragma unroll
      for (int m = 0; m < 12; ++m) {
        const float* p0 = tb + (24 * q + 2 * m) * CC + 6 * g + t;
        T2[t][m] = (floatx2){__expf(p0[0]), __expf(p0[CC])};
      }
  } else {
#pragma unroll
    for (int t = 0; t < 6; ++t) {
      const float* row = tb + (6 * g + t) * CC + 24 * q;
#pragma unroll
      for (int m = 0; m < 12; ++m)
        T2[t][m] = (floatx2){__expf(row[2 * m]), __expf(row[2 * m + 1])};
    }
  }

  const float4* e4 = (const float4*)emit;
  const int eidx = 6 * g + 2 * (q < 3 ? q : 2);
  float L = 0.f, pv = 1.f;

  // Synchronous chunk staging: 64 lanes stage 8x96 floats (3 float4 each).
#define STAGE_CHUNK(baserow, slot)                                        \
  {                                                                       \
    _Pragma("unroll") for (int u = 0; u < 3; ++u) {                       \
      int v = l + 64 * u;                                                 \
      int rw = v / 24, c4 = v - 24 * rw;                                  \
      float4 vv = e4[(((baserow) + rw) * BB + b) * 24 + c4];              \
      floatx4 o = {__expf(vv.x) * KAPPA, __expf(vv.y) * KAPPA,            \
                   __expf(vv.z) * KAPPA, __expf(vv.w) * KAPPA};           \
      *(floatx4*)&ebuf[slot][rw][c4 * 4] = o;                             \
    }                                                                     \
  }

#define INNER_DOT6(a0_, a1_, a2_, a3_, a4_, a5_)                          \
  float a0_, a1_, a2_, a3_, a4_, a5_;                                     \
  {                                                                       \
    const floatx4* up = (const floatx4*)&u_lds[24 * q];                   \
    floatx2 A0 = {0.f, 0.f}, A1 = {0.f, 0.f}, A2 = {0.f, 0.f};            \
    floatx2 A3 = {0.f, 0.f}, A4 = {0.f, 0.f}, A5 = {0.f, 0.f};            \
    floatx2 B0 = {0.f, 0.f}, B1 = {0.f, 0.f}, B2 = {0.f, 0.f};            \
    floatx2 B3 = {0.f, 0.f}, B4 = {0.f, 0.f}, B5 = {0.f, 0.f};            \
    _Pragma("unroll") for (int nn = 0; nn < 6; ++nn) {                    \
      floatx4 U = up[nn];                                                 \
      floatx2 lo2 = {U.x, U.y}, hi2 = {U.z, U.w};                         \
      A0 += lo2 * T2[0][2 * nn]; B0 += hi2 * T2[0][2 * nn + 1];           \
      A1 += lo2 * T2[1][2 * nn]; B1 += hi2 * T2[1][2 * nn + 1];           \
      A2 += lo2 * T2[2][2 * nn]; B2 += hi2 * T2[2][2 * nn + 1];           \
      A3 += lo2 * T2[3][2 * nn]; B3 += hi2 * T2[3][2 * nn + 1];           \
      A4 += lo2 * T2[4][2 * nn]; B4 += hi2 * T2[4][2 * nn + 1];           \
      A5 += lo2 * T2[5][2 * nn]; B5 += hi2 * T2[5][2 * nn + 1];           \
    }                                                                     \
    floatx2 S;                                                            \
    S = A0 + B0; a0_ = S.x + S.y;                                         \
    S = A1 + B1; a1_ = S.x + S.y;                                         \
    S = A2 + B2; a2_ = S.x + S.y;                                         \
    S = A3 + B3; a3_ = S.x + S.y;                                         \
    S = A4 + B4; a4_ = S.x + S.y;                                         \
    S = A5 + B5; a5_ = S.x + S.y;                                         \
    a0_ = qsum4(a0_); a1_ = qsum4(a1_); a2_ = qsum4(a2_);                 \
    a3_ = qsum4(a3_); a4_ = qsum4(a4_); a5_ = qsum4(a5_);                 \
  }

#define WRITE_U(a0_, a1_, a2_, a3_, a4_, a5_, Ex_, Ey_, invP_)            \
  {                                                                       \
    float wx = (q == 0) ? a0_ : ((q == 1) ? a2_ : a4_);                   \
    float wy = (q == 0) ? a1_ : ((q == 1) ? a3_ : a5_);                   \
    if (q < 3) {                                                          \
      floatx2 wv = {wx * (Ex_) * (invP_), wy * (Ey_) * (invP_)};          \
      *(floatx2*)&u_lds[6 * g + 2 * q] = wv;                              \
    }                                                                     \
  }

  if (isfw) {
    const int base0 = lo & ~7;
    STAGE_CHUNK(base0, (base0 >> 3) & 1);
    if (seg == 0) {
      float a00 = emit[(size_t)b * CC] + tstart[b * CC];
      L = a00;
      float v = emit[(size_t)b * CC + l] + tstart[b * CC + l];
      u_lds[l] = __expf(v - a00);
      if (l < 32) {
        int c2 = l + 64;
        float v2 = emit[(size_t)b * CC + c2] + tstart[b * CC + c2];
        u_lds[c2] = __expf(v2 - a00);
      }
    } else {
      u_lds[l] = 1.f;
      if (l < 32) u_lds[l + 64] = 1.f;
    }
    asm volatile("" ::: "memory");
    int jj = 1;
    for (int i = lo; i <= hi; ++i, ++jj) {
      if ((i & 7) == 0) {
        STAGE_CHUNK(i, (i >> 3) & 1);
        asm volatile("" ::: "memory");
      }
      float invP = 1.f;
      if ((jj & 3) == 0) { invP = 1.0f / pv; L += __logf(pv); }
      INNER_DOT6(a0, a1, a2, a3, a4, a5);
      floatx2 E = *(const floatx2*)&ebuf[(i >> 3) & 1][i & 7][eidx];
      float o0 = a0 * E.x * invP;  // lane 0: tag 0 (only lane 0's is used)
      if (((jj + 1) & 3) == 0) pv = bcast0(o0);
      WRITE_U(a0, a1, a2, a3, a4, a5, E.x, E.y, invP);
      asm volatile("" ::: "memory");
    }
  } else {
    const int cb = hi & ~7;
    STAGE_CHUNK(cb, (cb >> 3) & 1);
    asm volatile("" ::: "memory");
    // init w = E_hi * kappa (already staged)
    u_lds[l] = ebuf[(hi >> 3) & 1][hi & 7][l];
    if (l < 32) u_lds[l + 64] = ebuf[(hi >> 3) & 1][hi & 7][l + 64];
    asm volatile("" ::: "memory");
    int jj = 1;
    for (int i = hi; i >= lo; --i, ++jj) {
      if ((i & 7) == 0 && i > lo) {  // row i-1 crosses into lower chunk
        STAGE_CHUNK(i - 8, ((i >> 3) & 1) ^ 1);
        asm volatile("" ::: "memory");
      }
      float invP = 1.f;
      if ((jj & 3) == 0) { invP = 1.0f / pv; L += __logf(pv); }
      INNER_DOT6(a0, a1, a2, a3, a4, a5);
      floatx2 E = (i > lo)
          ? *(const floatx2*)&ebuf[((i - 1) >> 3) & 1][(i - 1) & 7][eidx]
          : (floatx2){1.f, 1.f};
      float o0 = a0 * E.x * invP;
      if (((jj + 1) & 3) == 0) pv = bcast0(o0);
      WRITE_U(a0, a1, a2, a3, a4, a5, E.x, E.y, invP);
      asm volatile("" ::: "memory");
    }
  }

  asm volatile("" ::: "memory");
  xout[l] = u_lds[l];
  if (l < 32) xout[l + 64] = u_lds[l + 64];
  if (l == 0) lsc[cid] = L + (float)n * NEG_LOG_KAPPA;
}

// ---------------- composition + score: 256 blocks x 1 wave ------------------
__global__ __launch_bounds__(64) void crf_compose(
    const float* __restrict__ emit, const int* __restrict__ target,
    const void* __restrict__ mask, const float* __restrict__ trans,
    const float* __restrict__ tstart, const float* __restrict__ tend,
    const float* __restrict__ xvec, const float* __restrict__ lsc,
    float* __restrict__ out) {
  const int b = blockIdx.x;
  const int l = threadIdx.x;
  const int len = get_len(mask, b, l);

  // telescope: x_s = a_s * e^{g_s} * (b_s . x_{s-1})/(b_s . 1)
  float Lam = lsc[b * CHPB + 0];
  const float* xcur = xvec + (size_t)(b * CHPB + 0) * CC;
  for (int s2 = 1; s2 < SEGS; ++s2) {
    if (s2 * SEGLEN + 1 > len - 1) break;  // empty segment = identity
    const float* bh = xvec + (size_t)(b * CHPB + (SEGS - 1) + s2) * CC;
    const float* ah = xvec + (size_t)(b * CHPB + s2) * CC;
    float pn = bh[l] * xcur[l];
    float pd = bh[l];
    if (l < 32) {
      pn += bh[l + 64] * xcur[l + 64];
      pd += bh[l + 64];
    }
    float num = wredf(pn), den = wredf(pd);
    Lam += __logf(num / den) + lsc[b * CHPB + s2];
    xcur = ah;
  }
  float zp = xcur[l] * __expf(tend[b * CC + l]);
  if (l < 32) zp += xcur[l + 64] * __expf(tend[b * CC + l + 64]);
  float logz = Lam + __logf(wredf(zp));

  // gold-path score
  const float* tb = trans + (size_t)b * (CC * CC);
  float sc = 0.f;
  for (int i = l; i < len; i += 64) {
    int tg = target[i * BB + b];
    sc += emit[((size_t)i * BB + b) * CC + tg];
    if (i >= 1) sc += tb[target[(i - 1) * BB + b] * CC + tg];
  }
  float score = wredf(sc);
  if (l == 0) {
    score += tstart[b * CC + target[b]] +
             tend[b * CC + target[(len - 1) * BB + b]];
    atomicAdd(out, (logz - score) * (1.0f / 256.0f));
  }
}

extern "C" void kernel_launch(void* const* d_in, const int* in_sizes, int n_in,
                              void* d_out, int out_size, void* d_ws, size_t ws_size,
                              hipStream_t stream) {
  const float* emit = (const float*)d_in[0];
  const float* hidden = (const float*)d_in[1];
  const int* target = (const int*)d_in[2];
  const void* mask = d_in[3];
  const float* Wt = (const float*)d_in[4];
  const float* bt = (const float*)d_in[5];
  const float* Ws = (const float*)d_in[6];
  const float* bs = (const float*)d_in[7];
  const float* We = (const float*)d_in[8];
  const float* be = (const float*)d_in[9];

  float* trans_ws = (float*)d_ws;                  // 256*9216
  float* ts_ws = trans_ws + (size_t)BB * CC * CC;  // 256*96
  float* te_ws = ts_ws + (size_t)BB * CC;          // 256*96
  float* xvec = te_ws + (size_t)BB * CC;           // 3840*96
  float* lsc = xvec + (size_t)BB * CHPB * CC;      // 3840

  hipMemsetAsync(d_out, 0, sizeof(float), stream);

  gemm_mfma<<<dim3((NTOT + 127) / 128, 2), 256, 0, stream>>>(
      hidden, Wt, Ws, We, bt, bs, be, trans_ws, ts_ws, te_ws);

  crf_chain<<<BB * CHPB, 64, 0, stream>>>(emit, mask, trans_ws, ts_ws, xvec, lsc);

  crf_compose<<<BB, 64, 0, stream>>>(emit, target, mask, trans_ws, ts_ws, te_ws,
                                     xvec, lsc, (float*)d_out);
}